// Round 8
// baseline (670.587 us; speedup 1.0000x reference)
//
#include <hip/hip_runtime.h>
#include <hip/hip_bf16.h>
#include <hip/hip_fp16.h>

#define NN 50000
#define EE 800000
#define FF 256
#define HH 256
#define CC 10
#define BB 128
#define VV 4
#define SS 16    // pooling strips per batch
#define NBLK 196 // ceil(NN/256)
#define BPV 12500 // blocks per view for prop kernels (NN/4)

typedef _Float16 half8v __attribute__((ext_vector_type(8)));
typedef float f32x4 __attribute__((ext_vector_type(4)));

// fp16 pack/unpack helpers
__device__ inline float2 h2f(unsigned int u) {
  __half2 h = *reinterpret_cast<__half2*>(&u);
  return __half22float2(h);
}
__device__ inline unsigned int f2h(float a, float b) {
  __half2 h = __floats2half2_rn(a, b);
  return *reinterpret_cast<unsigned int*>(&h);
}
// fp8 (OCP e4m3 on gfx950) pack/unpack: 4 values per uint
__device__ inline void fp8x4_to_f32(unsigned int u, float* f) {
  auto lo = __builtin_amdgcn_cvt_pk_f32_fp8(u, false);
  auto hi = __builtin_amdgcn_cvt_pk_f32_fp8(u, true);
  f[0] = lo[0]; f[1] = lo[1]; f[2] = hi[0]; f[3] = hi[1];
}
__device__ inline unsigned int f32x4_to_fp8(float a, float b, float c, float d) {
  int u = __builtin_amdgcn_cvt_pk_fp8_f32(a, b, 0, false);
  u = __builtin_amdgcn_cvt_pk_fp8_f32(c, d, u, true);
  return (unsigned int)u;
}

// ---------------- degree count (by row) ----------------
__global__ __launch_bounds__(256) void k_deg(const int* __restrict__ row, int* __restrict__ deg) {
  int i = blockIdx.x * 256 + threadIdx.x;
  if (i < EE) atomicAdd(&deg[row[i]], 1);
}

// ---------------- parallel scan: stage 1 block sums ----------------
__global__ __launch_bounds__(256) void k_scan1(const int* __restrict__ deg, int* __restrict__ bsum) {
  int i = blockIdx.x * 256 + threadIdx.x;
  int v = (i < NN) ? deg[i] : 0;
  for (int o = 32; o > 0; o >>= 1) v += __shfl_down(v, o, 64);
  __shared__ int ws[4];
  if ((threadIdx.x & 63) == 0) ws[threadIdx.x >> 6] = v;
  __syncthreads();
  if (threadIdx.x == 0) bsum[blockIdx.x] = ws[0] + ws[1] + ws[2] + ws[3];
}

// ---------------- parallel scan: stage 2 exclusive scan of block sums ----------------
__global__ __launch_bounds__(256) void k_scan2(const int* __restrict__ bsum, int* __restrict__ boff) {
  __shared__ int tmp[256];
  int tid = threadIdx.x;
  int v = (tid < NBLK) ? bsum[tid] : 0;
  tmp[tid] = v;
  __syncthreads();
  for (int o = 1; o < 256; o <<= 1) {
    int t = 0;
    if (tid >= o) t = tmp[tid - o];
    __syncthreads();
    if (tid >= o) tmp[tid] += t;
    __syncthreads();
  }
  if (tid < NBLK) boff[tid] = tmp[tid] - v;
}

// ---------------- parallel scan: stage 3 per-block scan + offset -> rptr ----------------
__global__ __launch_bounds__(256) void k_scan3(const int* __restrict__ deg,
                                               const int* __restrict__ boff,
                                               int* __restrict__ rptr) {
  __shared__ int tmp[256];
  int tid = threadIdx.x;
  int i = blockIdx.x * 256 + tid;
  int v = (i < NN) ? deg[i] : 0;
  tmp[tid] = v;
  __syncthreads();
  for (int o = 1; o < 256; o <<= 1) {
    int t = 0;
    if (tid >= o) t = tmp[tid - o];
    __syncthreads();
    if (tid >= o) tmp[tid] += t;
    __syncthreads();
  }
  int incl = tmp[tid];
  if (i < NN) rptr[i] = boff[blockIdx.x] + incl - v;
  if (i == NN - 1) rptr[NN] = boff[blockIdx.x] + incl;
}

// ---------------- scatter edges into CSR ----------------
__global__ __launch_bounds__(256) void k_scatter(const int* __restrict__ row,
                                                 const int* __restrict__ col,
                                                 const int* __restrict__ rptr,
                                                 int* __restrict__ fill,
                                                 int* __restrict__ csort) {
  int i = blockIdx.x * 256 + threadIdx.x;
  if (i < EE) {
    int r = row[i];
    int p = rptr[r] + atomicAdd(&fill[r], 1);
    csort[p] = col[i];
  }
}

// ---------------- batch_ptr via binary search (batch sorted) ----------------
__global__ __launch_bounds__(256) void k_bptr(const int* __restrict__ batch, int* __restrict__ bptr) {
  int b = threadIdx.x;
  if (b > BB) return;
  int lo = 0, hi = NN;
  while (lo < hi) { int mid = (lo + hi) >> 1; if (batch[mid] < b) lo = mid + 1; else hi = mid; }
  bptr[b] = lo;
}

// ---------------- pack 4 mask planes into float4 AoS ----------------
__global__ __launch_bounds__(256) void k_packm(const float* __restrict__ nmask, float4* __restrict__ m4) {
  int i = blockIdx.x * 256 + threadIdx.x;
  if (i < NN)
    m4[i] = make_float4(nmask[i], nmask[NN + i], nmask[2 * NN + i], nmask[3 * NN + i]);
}

// ---------------- pack W1 into MFMA B-fragment order (fp16) ----------------
__global__ __launch_bounds__(256) void k_wfrag(const float* __restrict__ W, _Float16* __restrict__ wf) {
  int id = blockIdx.x * 256 + threadIdx.x;  // 8*16*64 = 8192 frag-lanes
  if (id >= 8 * 16 * 64) return;
  int lane = id & 63;
  int t = (id >> 6) & 15;
  int ks = id >> 10;
  int n = t * 16 + (lane & 15);
  int k0 = ks * 32 + (lane >> 4) * 8;
  half8v v;
#pragma unroll
  for (int j = 0; j < 8; ++j) v[j] = (_Float16)W[(size_t)(k0 + j) * HH + n];
  reinterpret_cast<half8v*>(wf)[id] = v;
}

// ---------------- Y = (X .* DM) @ W1 -> fp16 via MFMA, no LDS ----------------
__global__ __launch_bounds__(256) void k_gemm(const float* __restrict__ X,
                                              const float* __restrict__ DM,
                                              const _Float16* __restrict__ wf,
                                              __half* __restrict__ Z) {
  int w = threadIdx.x >> 6, lane = threadIdx.x & 63;
  int arow = blockIdx.x * 64 + w * 16 + (lane & 15);
  bool valid = arow < NN;
  const half8v* wfv = reinterpret_cast<const half8v*>(wf);
  f32x4 acc[16];
#pragma unroll
  for (int t = 0; t < 16; ++t) acc[t] = (f32x4){0.f, 0.f, 0.f, 0.f};
  for (int ks = 0; ks < 8; ++ks) {
    int k0 = ks * 32 + (lane >> 4) * 8;
    half8v a;
    if (valid) {
      const float4* xp = reinterpret_cast<const float4*>(X + (size_t)arow * FF + k0);
      const float4* dp = reinterpret_cast<const float4*>(DM + (size_t)arow * FF + k0);
      float4 x0 = xp[0], x1 = xp[1], d0 = dp[0], d1 = dp[1];
      a[0] = (_Float16)(x0.x * d0.x); a[1] = (_Float16)(x0.y * d0.y);
      a[2] = (_Float16)(x0.z * d0.z); a[3] = (_Float16)(x0.w * d0.w);
      a[4] = (_Float16)(x1.x * d1.x); a[5] = (_Float16)(x1.y * d1.y);
      a[6] = (_Float16)(x1.z * d1.z); a[7] = (_Float16)(x1.w * d1.w);
    } else {
#pragma unroll
      for (int j = 0; j < 8; ++j) a[j] = (_Float16)0.f;
    }
#pragma unroll
    for (int t = 0; t < 16; ++t) {
      half8v b = wfv[(size_t)(ks * 16 + t) * 64 + lane];
      acc[t] = __builtin_amdgcn_mfma_f32_16x16x32_f16(a, b, acc[t], 0, 0, 0);
    }
  }
  int mrow = blockIdx.x * 64 + w * 16 + (lane >> 4) * 4;
  int ncol = lane & 15;
#pragma unroll
  for (int t = 0; t < 16; ++t) {
#pragma unroll
    for (int r = 0; r < 4; ++r) {
      int rr = mrow + r;
      if (rr < NN) Z[(size_t)rr * HH + t * 16 + ncol] = __float2half(acc[t][r]);
    }
  }
}

// ---------------- y fp16 -> fp8 plane ----------------
__global__ __launch_bounds__(256) void k_cvt8(const uint2* __restrict__ y2,
                                              unsigned int* __restrict__ y8) {
  int i = blockIdx.x * 256 + threadIdx.x;  // < NN*64
  uint2 raw = y2[i];
  float2 lo = h2f(raw.x), hi = h2f(raw.y);
  y8[i] = f32x4_to_fp8(lo.x, lo.y, hi.x, hi.y);
}

// ---------------- hop1 merged over views: gather y8, mask, write 4 planar planes ----------------
__global__ __launch_bounds__(256) void k_prop1(const unsigned int* __restrict__ y8,
                                               unsigned int* __restrict__ h8,
                                               const int* __restrict__ rptr,
                                               const int* __restrict__ csort,
                                               const float4* __restrict__ m4) {
  int node = blockIdx.x * 4 + (threadIdx.x >> 6);
  int lane = threadIdx.x & 63;
  int s = rptr[node], e = rptr[node + 1];
  float4 a0, a1, a2, a3;
  {
    float f[4];
    fp8x4_to_f32(y8[(size_t)node * 64 + lane], f);
    float4 m = m4[node];
    a0 = make_float4(f[0] * m.x, f[1] * m.x, f[2] * m.x, f[3] * m.x);
    a1 = make_float4(f[0] * m.y, f[1] * m.y, f[2] * m.y, f[3] * m.y);
    a2 = make_float4(f[0] * m.z, f[1] * m.z, f[2] * m.z, f[3] * m.z);
    a3 = make_float4(f[0] * m.w, f[1] * m.w, f[2] * m.w, f[3] * m.w);
  }
  int j = s;
  for (; j + 1 < e; j += 2) {
    int c0 = csort[j], c1 = csort[j + 1];
    float f0[4], f1[4];
    fp8x4_to_f32(y8[(size_t)c0 * 64 + lane], f0);
    fp8x4_to_f32(y8[(size_t)c1 * 64 + lane], f1);
    float4 p = m4[c0];
    float4 q = m4[c1];
    a0.x += f0[0] * p.x + f1[0] * q.x; a0.y += f0[1] * p.x + f1[1] * q.x;
    a0.z += f0[2] * p.x + f1[2] * q.x; a0.w += f0[3] * p.x + f1[3] * q.x;
    a1.x += f0[0] * p.y + f1[0] * q.y; a1.y += f0[1] * p.y + f1[1] * q.y;
    a1.z += f0[2] * p.y + f1[2] * q.y; a1.w += f0[3] * p.y + f1[3] * q.y;
    a2.x += f0[0] * p.z + f1[0] * q.z; a2.y += f0[1] * p.z + f1[1] * q.z;
    a2.z += f0[2] * p.z + f1[2] * q.z; a2.w += f0[3] * p.z + f1[3] * q.z;
    a3.x += f0[0] * p.w + f1[0] * q.w; a3.y += f0[1] * p.w + f1[1] * q.w;
    a3.z += f0[2] * p.w + f1[2] * q.w; a3.w += f0[3] * p.w + f1[3] * q.w;
  }
  if (j < e) {
    int c0 = csort[j];
    float f0[4];
    fp8x4_to_f32(y8[(size_t)c0 * 64 + lane], f0);
    float4 p = m4[c0];
    a0.x += f0[0] * p.x; a0.y += f0[1] * p.x; a0.z += f0[2] * p.x; a0.w += f0[3] * p.x;
    a1.x += f0[0] * p.y; a1.y += f0[1] * p.y; a1.z += f0[2] * p.y; a1.w += f0[3] * p.y;
    a2.x += f0[0] * p.z; a2.y += f0[1] * p.z; a2.z += f0[2] * p.z; a2.w += f0[3] * p.z;
    a3.x += f0[0] * p.w; a3.y += f0[1] * p.w; a3.z += f0[2] * p.w; a3.w += f0[3] * p.w;
  }
  float sc = 1.0f / (float)(e - s + 1);
  size_t base = (size_t)node * 64 + lane;
  h8[base] = f32x4_to_fp8(a0.x * sc, a0.y * sc, a0.z * sc, a0.w * sc);
  h8[(size_t)NN * 64 + base] = f32x4_to_fp8(a1.x * sc, a1.y * sc, a1.z * sc, a1.w * sc);
  h8[(size_t)2 * NN * 64 + base] = f32x4_to_fp8(a2.x * sc, a2.y * sc, a2.z * sc, a2.w * sc);
  h8[(size_t)3 * NN * 64 + base] = f32x4_to_fp8(a3.x * sc, a3.y * sc, a3.z * sc, a3.w * sc);
}

// ---------------- hop2, per-view planar (view = blockIdx.x / BPV) ----------------
__global__ __launch_bounds__(256) void k_prop2v(const unsigned int* __restrict__ in,
                                                unsigned int* __restrict__ out,
                                                const int* __restrict__ rptr,
                                                const int* __restrict__ csort) {
  int v = blockIdx.x / BPV;
  int quad = blockIdx.x - v * BPV;
  int node = quad * 4 + (threadIdx.x >> 6);
  int lane = threadIdx.x & 63;
  const unsigned int* ip = in + (size_t)v * NN * 64;
  int s = rptr[node], e = rptr[node + 1];
  float4 acc;
  {
    float f[4];
    fp8x4_to_f32(ip[(size_t)node * 64 + lane], f);
    acc = make_float4(f[0], f[1], f[2], f[3]);
  }
  int j = s;
  for (; j + 3 < e; j += 4) {
    int c0 = csort[j], c1 = csort[j + 1], c2 = csort[j + 2], c3 = csort[j + 3];
    unsigned int r0 = ip[(size_t)c0 * 64 + lane];
    unsigned int r1 = ip[(size_t)c1 * 64 + lane];
    unsigned int r2 = ip[(size_t)c2 * 64 + lane];
    unsigned int r3 = ip[(size_t)c3 * 64 + lane];
    float f0[4], f1[4], f2[4], f3[4];
    fp8x4_to_f32(r0, f0); fp8x4_to_f32(r1, f1);
    fp8x4_to_f32(r2, f2); fp8x4_to_f32(r3, f3);
    acc.x += f0[0] + f1[0] + f2[0] + f3[0];
    acc.y += f0[1] + f1[1] + f2[1] + f3[1];
    acc.z += f0[2] + f1[2] + f2[2] + f3[2];
    acc.w += f0[3] + f1[3] + f2[3] + f3[3];
  }
  for (; j < e; ++j) {
    int c0 = csort[j];
    float f[4];
    fp8x4_to_f32(ip[(size_t)c0 * 64 + lane], f);
    acc.x += f[0]; acc.y += f[1]; acc.z += f[2]; acc.w += f[3];
  }
  float sc = 1.0f / (float)(e - s + 1);
  out[(size_t)v * NN * 64 + (size_t)node * 64 + lane] =
      f32x4_to_fp8(acc.x * sc, acc.y * sc, acc.z * sc, acc.w * sc);
}

// ---------------- hop3 per-view planar + bias + relu + pool ----------------
__global__ __launch_bounds__(256) void k_prop3v(const unsigned int* __restrict__ in,
                                                const int* __restrict__ rptr,
                                                const int* __restrict__ csort,
                                                const int* __restrict__ batch,
                                                const float* __restrict__ b1,
                                                float* __restrict__ part) {
  int v = blockIdx.x / BPV;
  int quad = blockIdx.x - v * BPV;
  int w = threadIdx.x >> 6, lane = threadIdx.x & 63;
  int node = quad * 4 + w;
  __shared__ float red[4][HH];
  __shared__ int bb[4];
  const unsigned int* ip = in + (size_t)v * NN * 64;
  int s = rptr[node], e = rptr[node + 1];
  float4 acc;
  {
    float f[4];
    fp8x4_to_f32(ip[(size_t)node * 64 + lane], f);
    acc = make_float4(f[0], f[1], f[2], f[3]);
  }
  int j = s;
  for (; j + 3 < e; j += 4) {
    int c0 = csort[j], c1 = csort[j + 1], c2 = csort[j + 2], c3 = csort[j + 3];
    unsigned int r0 = ip[(size_t)c0 * 64 + lane];
    unsigned int r1 = ip[(size_t)c1 * 64 + lane];
    unsigned int r2 = ip[(size_t)c2 * 64 + lane];
    unsigned int r3 = ip[(size_t)c3 * 64 + lane];
    float f0[4], f1[4], f2[4], f3[4];
    fp8x4_to_f32(r0, f0); fp8x4_to_f32(r1, f1);
    fp8x4_to_f32(r2, f2); fp8x4_to_f32(r3, f3);
    acc.x += f0[0] + f1[0] + f2[0] + f3[0];
    acc.y += f0[1] + f1[1] + f2[1] + f3[1];
    acc.z += f0[2] + f1[2] + f2[2] + f3[2];
    acc.w += f0[3] + f1[3] + f2[3] + f3[3];
  }
  for (; j < e; ++j) {
    int c0 = csort[j];
    float f[4];
    fp8x4_to_f32(ip[(size_t)c0 * 64 + lane], f);
    acc.x += f[0]; acc.y += f[1]; acc.z += f[2]; acc.w += f[3];
  }
  float sc = 1.0f / (float)(e - s + 1);
  float4 bv = *reinterpret_cast<const float4*>(&b1[lane * 4]);
  red[w][lane * 4 + 0] = fmaxf(acc.x * sc + bv.x, 0.f);
  red[w][lane * 4 + 1] = fmaxf(acc.y * sc + bv.y, 0.f);
  red[w][lane * 4 + 2] = fmaxf(acc.z * sc + bv.z, 0.f);
  red[w][lane * 4 + 3] = fmaxf(acc.w * sc + bv.w, 0.f);
  if (lane == 0) bb[w] = batch[node];
  __syncthreads();
  int strip = quad & (SS - 1);
  float* pp = part + (size_t)v * SS * BB * HH;
  if (bb[0] == bb[1] && bb[1] == bb[2] && bb[2] == bb[3]) {
    int col = threadIdx.x;
    float sum = red[0][col] + red[1][col] + red[2][col] + red[3][col];
    atomicAdd(&pp[((size_t)strip * BB + bb[0]) * HH + col], sum);
  } else {
    int b = bb[w];
#pragma unroll
    for (int k = 0; k < 4; ++k)
      atomicAdd(&pp[((size_t)strip * BB + b) * HH + lane * 4 + k], red[w][lane * 4 + k]);
  }
}

// ---------------- head: meanpool -> @W2+b2 -> @Wc+bc -> softmax ----------------
__global__ __launch_bounds__(256) void k_head(const float* __restrict__ part,
                                              const int* __restrict__ bptr,
                                              const float* __restrict__ W2,
                                              const float* __restrict__ b2,
                                              const float* __restrict__ Wc,
                                              const float* __restrict__ bc,
                                              float* __restrict__ probs,
                                              float* __restrict__ logits) {
  int v = blockIdx.x / BB;
  int b = blockIdx.x % BB;
  int h = threadIdx.x;
  __shared__ float mr[HH];
  __shared__ float vr[HH];
  __shared__ float scs[CC];
  float acc = 0.f;
  for (int s = 0; s < SS; ++s)
    acc += part[(((size_t)v * SS + s) * BB + b) * HH + h];
  int cnt = bptr[b + 1] - bptr[b]; if (cnt < 1) cnt = 1;
  mr[h] = acc / (float)cnt;
  __syncthreads();
  float a = b2[h];
  for (int k = 0; k < HH; ++k) a += mr[k] * W2[k * HH + h];
  vr[h] = a;
  __syncthreads();
  if (h < CC) {
    float t = bc[h];
    for (int k = 0; k < HH; ++k) t += vr[k] * Wc[k * CC + h];
    scs[h] = t;
  }
  __syncthreads();
  if (h < CC) {
    float m = scs[0];
    for (int c = 1; c < CC; ++c) m = fmaxf(m, scs[c]);
    float den = 0.f;
    for (int c = 0; c < CC; ++c) den += expf(scs[c] - m);
    float p = expf(scs[h] - m) / den;
    probs[((size_t)v * BB + b) * CC + h] = p;
    if (v == 0) logits[b * CC + h] = scs[h];
  }
}

// ---------------- loss: consistency + entropy ----------------
__global__ __launch_bounds__(256) void k_loss(const float* __restrict__ probs, float* __restrict__ out) {
  __shared__ float mp[BB * CC];
  __shared__ float red[8];
  int tid = threadIdx.x;
  float ent = 0.f;
  for (int i = tid; i < BB * CC; i += 256) {
    float m = 0.25f * (probs[i] + probs[BB * CC + i] + probs[2 * BB * CC + i] + probs[3 * BB * CC + i]);
    mp[i] = m;
    ent += m * logf(m + 1e-8f);
  }
  __syncthreads();
  float cons = 0.f;
  for (int i = tid; i < VV * BB * CC; i += 256) {
    float d = probs[i] - mp[i % (BB * CC)];
    cons += d * d;
  }
  for (int o = 32; o > 0; o >>= 1) {
    cons += __shfl_down(cons, o, 64);
    ent += __shfl_down(ent, o, 64);
  }
  int wid = tid >> 6, lane = tid & 63;
  if (lane == 0) { red[wid] = cons; red[4 + wid] = ent; }
  __syncthreads();
  if (tid == 0) {
    float c = red[0] + red[1] + red[2] + red[3];
    float e2 = red[4] + red[5] + red[6] + red[7];
    out[0] = c / (float)(VV * BB) - e2 / (float)BB;
  }
}

extern "C" void kernel_launch(void* const* d_in, const int* in_sizes, int n_in,
                              void* d_out, int out_size, void* d_ws, size_t ws_size,
                              hipStream_t stream) {
  const float* x     = (const float*)d_in[0];
  const int*   erow  = (const int*)d_in[1];          // edge_index[0]
  const int*   ecol  = ((const int*)d_in[1]) + EE;   // edge_index[1]
  const int*   batch = (const int*)d_in[2];
  const float* dm    = (const float*)d_in[3];
  const float* nmask = (const float*)d_in[4];
  const float* W1    = (const float*)d_in[5];
  const float* b1    = (const float*)d_in[6];
  const float* W2    = (const float*)d_in[7];
  const float* b2    = (const float*)d_in[8];
  const float* Wc    = (const float*)d_in[9];
  const float* bc    = (const float*)d_in[10];
  float* out = (float*)d_out;

  char* ws = (char*)d_ws;
  size_t off = 0;
  auto carve = [&](size_t bytes) -> char* {
    char* p = ws + off;
    off = (off + bytes + 255) & ~(size_t)255;
    return p;
  };
  float* part  = (float*)carve((size_t)VV * SS * BB * HH * 4);
  int*   deg   = (int*)carve((size_t)NN * 4);
  int*   fill  = (int*)carve((size_t)NN * 4);
  int*   rptr  = (int*)carve((size_t)(NN + 1) * 4);
  int*   csort = (int*)carve((size_t)EE * 4);
  int*   bptr  = (int*)carve((size_t)(BB + 1) * 4);
  int*   bsum  = (int*)carve(256 * 4);
  int*   boff  = (int*)carve(256 * 4);
  float* probs = (float*)carve((size_t)VV * BB * CC * 4);
  float4* m4   = (float4*)carve((size_t)NN * 16);
  _Float16* wf = (_Float16*)carve((size_t)8 * 16 * 64 * 8 * 2);  // 128 KB

  const size_t NFh = (size_t)NN * FF * 2;  // 25.6 MB fp16 node-feature plane
  __half* y  = (__half*)carve(NFh);                           // GEMM out (fp16)
  unsigned int* y8 = (unsigned int*)carve((size_t)NN * 256);  // 12.8 MB fp8 plane
  unsigned int* h8  = (unsigned int*)carve((size_t)VV * NN * 256);  // 51.2 MB, 4 planar fp8 planes
  unsigned int* h8b = (unsigned int*)carve((size_t)VV * NN * 256);  // 51.2 MB

  hipMemsetAsync(deg, 0, (size_t)NN * 4, stream);
  hipMemsetAsync(fill, 0, (size_t)NN * 4, stream);
  hipMemsetAsync(part, 0, (size_t)VV * SS * BB * HH * 4, stream);

  k_deg<<<(EE + 255) / 256, 256, 0, stream>>>(erow, deg);
  k_scan1<<<NBLK, 256, 0, stream>>>(deg, bsum);
  k_scan2<<<1, 256, 0, stream>>>(bsum, boff);
  k_scan3<<<NBLK, 256, 0, stream>>>(deg, boff, rptr);
  k_scatter<<<(EE + 255) / 256, 256, 0, stream>>>(erow, ecol, rptr, fill, csort);
  k_bptr<<<1, 256, 0, stream>>>(batch, bptr);
  k_packm<<<(NN + 255) / 256, 256, 0, stream>>>(nmask, m4);
  k_wfrag<<<32, 256, 0, stream>>>(W1, wf);

  k_gemm<<<(NN + 63) / 64, 256, 0, stream>>>(x, dm, wf, y);
  k_cvt8<<<(NN * 64) / 256, 256, 0, stream>>>((const uint2*)y, y8);
  k_prop1<<<BPV, 256, 0, stream>>>(y8, h8, rptr, csort, m4);
  k_prop2v<<<BPV * VV, 256, 0, stream>>>(h8, h8b, rptr, csort);
  k_prop3v<<<BPV * VV, 256, 0, stream>>>(h8b, rptr, csort, batch, b1, part);
  k_head<<<VV * BB, 256, 0, stream>>>(part, bptr, W2, b2, Wc, bc, probs, out);
  k_loss<<<1, 256, 0, stream>>>(probs, out + BB * CC);
}